// Round 6
// baseline (1807.349 us; speedup 1.0000x reference)
//
#include <hip/hip_runtime.h>
#include <hip/hip_bf16.h>
#include <hip/hip_fp16.h>

#define B_    8192
#define D_    1024
#define H_    4096
#define DOUT_ 1024
#define E_    8
#define MAXR  17408   // 16384 assignments + 8*128 padding

typedef float    f32x4 __attribute__((ext_vector_type(4)));
typedef _Float16 f16x8 __attribute__((ext_vector_type(8)));
typedef unsigned short u16;
typedef u16      u16x8 __attribute__((ext_vector_type(8)));
typedef u16      u16x4 __attribute__((ext_vector_type(4)));
typedef unsigned int u32;

__device__ __forceinline__ u16 f2h_bits(float f) {
  _Float16 h = (_Float16)f;
  return __builtin_bit_cast(u16, h);
}

// tanh-form gelu (max abs err vs erf-gelu ~3e-4; threshold margin 4x)
__device__ __forceinline__ float gelu_f(float v) {
  float z = 0.7978845608028654f * (v + 0.044715f * v * v * v);
  float ez = __expf(2.f * z);
  float th = 1.f - 2.f / (ez + 1.f);
  return 0.5f * v * (1.f + th);
}

// ---- workspace layout (bytes) ----
#define OFF_TOPI 512                       // int[16384]
#define OFF_TOPW (OFF_TOPI + 65536)        // float[16384]
#define OFF_ATOK (OFF_TOPW + 65536)        // int[17408]
#define OFF_WSL  (OFF_ATOK + 69632)        // float[17408]
#define OFF_XG   524288                    // u16[17408*1024] f16 (dead after gemm1)
#define OFF_W1T  (OFF_XG + 35651584)       // u16[8*4096*1024] f16 (dead after gemm1)
#define OFF_W2T  OFF_XG                    // u16[8*1024*4096] f16, ALIASES Xg+W1t
#define OFF_HB   (OFF_W1T + 67108864)      // u16[17408*4096] f16
// end = 245,891,072 bytes

__global__ void k_zero_out(float* __restrict__ out) {
  size_t i = (size_t)(blockIdx.x * 256 + threadIdx.x) * 4;
  *(f32x4*)&out[i] = (f32x4){0.f, 0.f, 0.f, 0.f};
}

__global__ void k_init(int* __restrict__ atok, float* __restrict__ wslot,
                       int* __restrict__ meta) {
  int i = blockIdx.x * 256 + threadIdx.x;
  if (i < MAXR) { atok[i] = 0; wslot[i] = 0.f; }
  if (blockIdx.x == 0 && threadIdx.x < 64) meta[threadIdx.x] = 0;
}

__global__ __launch_bounds__(256) void k_gate(
    const float* __restrict__ x, const float* __restrict__ Wg,
    const float* __restrict__ bg, int* __restrict__ counts,
    float* __restrict__ usage, int* __restrict__ topi, float* __restrict__ topw) {
  __shared__ float su[E_];
  if (threadIdx.x < E_) su[threadIdx.x] = 0.f;
  __syncthreads();
  const int lane = threadIdx.x & 63;
  const int b = blockIdx.x * 4 + (threadIdx.x >> 6);
  float p[E_] = {0.f,0.f,0.f,0.f,0.f,0.f,0.f,0.f};
  #pragma unroll
  for (int j = 0; j < 4; ++j) {
    int d = j * 256 + lane * 4;
    float4 xv = *(const float4*)&x[(size_t)b * D_ + d];
    const float* wr = &Wg[(size_t)d * E_];
    #pragma unroll
    for (int c = 0; c < 4; ++c) {
      float xc = reinterpret_cast<const float*>(&xv)[c];
      #pragma unroll
      for (int e = 0; e < E_; ++e) p[e] += xc * wr[c * E_ + e];
    }
  }
  #pragma unroll
  for (int off = 32; off >= 1; off >>= 1)
    #pragma unroll
    for (int e = 0; e < E_; ++e) p[e] += __shfl_xor(p[e], off, 64);
  float mx = -1e30f;
  #pragma unroll
  for (int e = 0; e < E_; ++e) { p[e] += bg[e]; mx = fmaxf(mx, p[e]); }
  int i0 = 0; float l0 = p[0];
  #pragma unroll
  for (int e = 1; e < E_; ++e) if (p[e] > l0) { l0 = p[e]; i0 = e; }
  int i1 = -1; float l1 = -1e30f;
  #pragma unroll
  for (int e = 0; e < E_; ++e) if (e != i0 && p[e] > l1) { l1 = p[e]; i1 = e; }
  float s = 0.f;
  #pragma unroll
  for (int e = 0; e < E_; ++e) { p[e] = expf(p[e] - mx); s += p[e]; }
  float inv = 1.f / s;
  if (lane == 0) {
    float e0 = expf(l0 - mx), e1 = expf(l1 - mx);
    float wsum = e0 + e1;
    topi[b * 2] = i0; topi[b * 2 + 1] = i1;
    topw[b * 2] = e0 / wsum; topw[b * 2 + 1] = e1 / wsum;
    atomicAdd(&counts[i0], 1);
    atomicAdd(&counts[i1], 1);
    #pragma unroll
    for (int e = 0; e < E_; ++e) atomicAdd(&su[e], p[e] * inv);
  }
  __syncthreads();
  if (threadIdx.x < E_) atomicAdd(&usage[threadIdx.x], su[threadIdx.x]);
}

__global__ void k_scan_aux(const int* __restrict__ counts, int* __restrict__ offsets,
                           const float* __restrict__ usage, float* __restrict__ auxp) {
  if (threadIdx.x == 0) {
    int off = 0;
    for (int e = 0; e < E_; ++e) { offsets[e] = off; off += (counts[e] + 127) & ~127; }
    offsets[E_] = off;
    float aux = 0.f;
    const float lu = logf(1.0f / (float)E_);
    for (int e = 0; e < E_; ++e) {
      float u = usage[e] * (1.0f / (float)B_);
      aux += u * lu - logf(u) * (1.0f / (float)E_);
    }
    *auxp = aux;
  }
}

__global__ void k_scatter(const int* __restrict__ topi, const float* __restrict__ topw,
                          const int* __restrict__ offsets, int* __restrict__ cursors,
                          int* __restrict__ atok, float* __restrict__ wslot) {
  int b = blockIdx.x * 256 + threadIdx.x;
  if (b >= B_) return;
  #pragma unroll
  for (int k = 0; k < 2; ++k) {
    int e = topi[b * 2 + k];
    int pos = atomicAdd(&cursors[e], 1);
    int slot = offsets[e] + pos;
    atok[slot] = b;
    wslot[slot] = topw[b * 2 + k];
  }
}

__global__ __launch_bounds__(256) void k_gather(const float* __restrict__ x,
                                                const int* __restrict__ atok,
                                                u16* __restrict__ Xg) {
  int slot = blockIdx.x;
  int tok = atok[slot];
  int c = threadIdx.x * 4;
  float4 v = *(const float4*)&x[(size_t)tok * D_ + c];
  const float* vf = reinterpret_cast<const float*>(&v);
  u16x4 o;
  o.x = f2h_bits(vf[0]); o.y = f2h_bits(vf[1]);
  o.z = f2h_bits(vf[2]); o.w = f2h_bits(vf[3]);
  *(u16x4*)&Xg[(size_t)slot * D_ + c] = o;
}

// convert + transpose: src [E][K][N] fp32  ->  dst [E][N][K] f16. 64x64 tiles.
__global__ __launch_bounds__(256) void k_cvt_t(const float* __restrict__ src,
                                               u16* __restrict__ dst, int K, int N) {
  const int e = blockIdx.z;
  const int kt = blockIdx.x * 64;
  const int nt = blockIdx.y * 64;
  __shared__ u16 t[64][68];
  const float* s = src + (size_t)e * K * N;
  u16* d = dst + (size_t)e * N * K;
  const int tr = threadIdx.x >> 4;
  const int tc = threadIdx.x & 15;
  #pragma unroll
  for (int i = 0; i < 4; ++i) {
    int k = tr + i * 16;
    float4 v = *(const float4*)&s[(size_t)(kt + k) * N + nt + tc * 4];
    t[k][tc*4+0] = f2h_bits(v.x); t[k][tc*4+1] = f2h_bits(v.y);
    t[k][tc*4+2] = f2h_bits(v.z); t[k][tc*4+3] = f2h_bits(v.w);
  }
  __syncthreads();
  #pragma unroll
  for (int i = 0; i < 4; ++i) {
    int n = tr + i * 16;
    u16x4 o;
    o.x = t[tc*4+0][n]; o.y = t[tc*4+1][n];
    o.z = t[tc*4+2][n]; o.w = t[tc*4+3][n];
    *(u16x4*)&d[(size_t)(nt + n) * K + kt + tc * 4] = o;
  }
}

#define GLDS(g, l) __builtin_amdgcn_global_load_lds( \
    (const u32 __attribute__((address_space(1)))*)(g), \
    (u32 __attribute__((address_space(3)))*)(l), 16, 0, 0)

// ---- 256x256 tile, BK=64, swizzled LDS (linear dest + pre-swizzled source) --
// LDS tile: 256 rows x 64 u16 (128B rows). Content: LDS[row][chk] = src[row][chk^(row&7)]
// (16B chunks). Stage: lane l of segment writes chunk (l&7), so it loads source
// chunk (l&7)^(l>>3) of row seg*8+(l>>3). Read XORs the same involution.
#define STG(Ap, Bp, LD, kk, Ad, Bd, Alim) do { \
  const int rl_ = lane >> 3; \
  const int chk_ = ((lane & 7) ^ rl_) * 8; \
  _Pragma("unroll") \
  for (int c = 0; c < 4; ++c) { \
    int seg = wid * 4 + c; \
    int rowA = seg * 8 + rl_; if (rowA > (Alim)) rowA = (Alim); \
    int rowB = seg * 8 + rl_; \
    GLDS((Ap) + (size_t)rowA * (LD) + (kk) + chk_, (Ad) + seg * 512); \
    GLDS((Bp) + (size_t)rowB * (LD) + (kk) + chk_, (Bd) + seg * 512); \
  } } while (0)

// wave-tile 128x64 (2M x 4N waves): per tile 16 A-frags + 8 B-frags, 64 MFMA
#define CMP(As, Bs) do { \
  _Pragma("unroll") \
  for (int ks = 0; ks < 2; ++ks) { \
    const int coff = ((ks * 4 + (lane >> 4)) ^ (lane & 7)) * 8; \
    f16x8 af[8], bf[4]; \
    _Pragma("unroll") \
    for (int m = 0; m < 8; ++m) \
      af[m] = *(const f16x8*)&(As)[(wr * 128 + m * 16 + (lane & 15)) * 64 + coff]; \
    _Pragma("unroll") \
    for (int n = 0; n < 4; ++n) \
      bf[n] = *(const f16x8*)&(Bs)[(wc * 64 + n * 16 + (lane & 15)) * 64 + coff]; \
    _Pragma("unroll") \
    for (int m = 0; m < 8; ++m) \
      _Pragma("unroll") \
      for (int n = 0; n < 4; ++n) \
        acc[m][n] = __builtin_amdgcn_mfma_f32_16x16x32_f16(af[m], bf[n], acc[m][n], 0, 0, 0); \
  } } while (0)

// GEMM1: Hb[slot][n] = gelu( Xg[slot][:] @ W1t[e][n][:]^T + b1[e][n] )  (f16 out)
__global__ __launch_bounds__(512, 2) void k_gemm1(
    const u16* __restrict__ Xg, const u16* __restrict__ W1t,
    const float* __restrict__ b1, const int* __restrict__ offsets,
    u16* __restrict__ Hb) {
  const int e  = blockIdx.x >> 6;
  const int mt = blockIdx.x & 63;
  const int roff = offsets[e];
  const int rend = offsets[e + 1];
  const int pn = rend - roff;
  const int row0 = mt * 256;
  if (row0 >= pn) return;
  const int n0 = blockIdx.y * 256;
  const int tid = threadIdx.x, lane = tid & 63, wid = tid >> 6;
  const int wr = wid >> 2, wc = wid & 3;        // 2M x 4N waves
  const int Alim = (MAXR - 1) - (roff + row0);  // clamp A-rows inside workspace
  __shared__ __align__(16) u16 As0[16384], Bs0[16384], As1[16384], Bs1[16384];
  f32x4 acc[8][4] = {};
  const u16* Ap = Xg + (size_t)(roff + row0) * D_;
  const u16* Bp = W1t + (size_t)e * H_ * D_ + (size_t)n0 * D_;

  STG(Ap, Bp, D_, 0, As0, Bs0, Alim);
  __syncthreads();
  for (int t = 0; t < 16; t += 2) {
    STG(Ap, Bp, D_, (t + 1) * 64, As1, Bs1, Alim);
    CMP(As0, Bs0);
    __syncthreads();
    if (t + 2 < 16) STG(Ap, Bp, D_, (t + 2) * 64, As0, Bs0, Alim);
    CMP(As1, Bs1);
    __syncthreads();
  }
  const int rhi = (lane >> 4) * 4, cix = lane & 15;
  #pragma unroll
  for (int n = 0; n < 4; ++n) {
    int lc = wc * 64 + n * 16 + cix;
    float bv = b1[e * H_ + n0 + lc];
    #pragma unroll
    for (int m = 0; m < 8; ++m) {
      #pragma unroll
      for (int j = 0; j < 4; ++j) {
        int lr = wr * 128 + m * 16 + rhi + j;
        int gr = roff + row0 + lr;
        if (gr < rend)
          Hb[(size_t)gr * H_ + (n0 + lc)] = f2h_bits(gelu_f(acc[m][n][j] + bv));
      }
    }
  }
}

// GEMM2: out[tok][n] += wslot * ( Hb[slot][:] @ W2t[e][n][:]^T + b2[e][n] )
// 256x256 tile, K-split=2 (kbase 0 / 2048), atomic combine.
__global__ __launch_bounds__(512, 2) void k_gemm2(
    const u16* __restrict__ Hb, const u16* __restrict__ W2t,
    const float* __restrict__ b2, const int* __restrict__ offsets,
    const int* __restrict__ atok, const float* __restrict__ wslot,
    float* __restrict__ out) {
  const int e  = blockIdx.x >> 6;
  const int mt = blockIdx.x & 63;
  const int roff = offsets[e];
  const int rend = offsets[e + 1];
  const int pn = rend - roff;
  const int row0 = mt * 256;
  if (row0 >= pn) return;
  const int n0 = blockIdx.y * 256;
  const int kbase = blockIdx.z * 2048;
  const int tid = threadIdx.x, lane = tid & 63, wid = tid >> 6;
  const int wr = wid >> 2, wc = wid & 3;
  const int Alim = (MAXR - 1) - (roff + row0);
  __shared__ __align__(16) u16 As0[16384], Bs0[16384], As1[16384], Bs1[16384];
  f32x4 acc[8][4] = {};
  const u16* Ap = Hb + (size_t)(roff + row0) * H_ + kbase;
  const u16* Bp = W2t + (size_t)e * DOUT_ * H_ + (size_t)n0 * H_ + kbase;

  STG(Ap, Bp, H_, 0, As0, Bs0, Alim);
  __syncthreads();
  for (int t = 0; t < 32; t += 2) {
    STG(Ap, Bp, H_, (t + 1) * 64, As1, Bs1, Alim);
    CMP(As0, Bs0);
    __syncthreads();
    if (t + 2 < 32) STG(Ap, Bp, H_, (t + 2) * 64, As0, Bs0, Alim);
    CMP(As1, Bs1);
    __syncthreads();
  }
  const int rhi = (lane >> 4) * 4, cix = lane & 15;
  const int first = (kbase == 0);
  float bv[4];
  #pragma unroll
  for (int n = 0; n < 4; ++n) bv[n] = b2[e * DOUT_ + n0 + wc * 64 + n * 16 + cix];
  #pragma unroll
  for (int m = 0; m < 8; ++m) {
    #pragma unroll
    for (int j = 0; j < 4; ++j) {
      int lr = wr * 128 + m * 16 + rhi + j;
      int slot = roff + row0 + lr;
      if (slot >= rend) continue;        // row belongs to next expert's region
      float w = wslot[slot];
      if (w == 0.f) continue;            // padding slot
      int tok = atok[slot];
      float* orow = out + (size_t)tok * DOUT_ + n0;
      #pragma unroll
      for (int n = 0; n < 4; ++n) {
        int lc = wc * 64 + n * 16 + cix;
        float v = first ? w * (acc[m][n][j] + bv[n]) : w * acc[m][n][j];
        atomicAdd(&orow[lc], v);
      }
    }
  }
}

extern "C" void kernel_launch(void* const* d_in, const int* in_sizes, int n_in,
                              void* d_out, int out_size, void* d_ws, size_t ws_size,
                              hipStream_t stream) {
  const float* x  = (const float*)d_in[0];
  const float* Wg = (const float*)d_in[1];
  const float* bg = (const float*)d_in[2];
  const float* W1 = (const float*)d_in[3];
  const float* b1 = (const float*)d_in[4];
  const float* W2 = (const float*)d_in[5];
  const float* b2 = (const float*)d_in[6];
  float* out = (float*)d_out;

  char* ws = (char*)d_ws;
  int*   counts  = (int*)(ws + 0);
  int*   cursors = (int*)(ws + 32);
  int*   offsets = (int*)(ws + 64);
  float* usage   = (float*)(ws + 128);
  int*   topi    = (int*)(ws + OFF_TOPI);
  float* topw    = (float*)(ws + OFF_TOPW);
  int*   atok    = (int*)(ws + OFF_ATOK);
  float* wslot   = (float*)(ws + OFF_WSL);
  u16*   Xg      = (u16*)(ws + OFF_XG);
  u16*   W1t     = (u16*)(ws + OFF_W1T);
  u16*   W2t     = (u16*)(ws + OFF_W2T);
  u16*   Hb      = (u16*)(ws + OFF_HB);

  k_zero_out<<<B_ * DOUT_ / 1024, 256, 0, stream>>>(out);
  k_init<<<(MAXR + 255) / 256, 256, 0, stream>>>(atok, wslot, (int*)ws);
  k_gate<<<B_ / 4, 256, 0, stream>>>(x, Wg, bg, counts, usage, topi, topw);
  k_scan_aux<<<1, 64, 0, stream>>>(counts, offsets, usage, out + (size_t)B_ * DOUT_);
  k_scatter<<<B_ / 256, 256, 0, stream>>>(topi, topw, offsets, cursors, atok, wslot);
  k_gather<<<MAXR, 256, 0, stream>>>(x, atok, Xg);
  k_cvt_t<<<dim3(D_ / 64, H_ / 64, E_), 256, 0, stream>>>(W1, W1t, D_, H_);
  k_gemm1<<<dim3(E_ * 64, H_ / 256), 512, 0, stream>>>(Xg, W1t, b1, offsets, Hb);
  k_cvt_t<<<dim3(H_ / 64, DOUT_ / 64, E_), 256, 0, stream>>>(W2, W2t, H_, DOUT_);
  k_gemm2<<<dim3(E_ * 64, DOUT_ / 256, 2), 512, 0, stream>>>(Hb, W2t, b2, offsets, atok, wslot, out);
}

// Round 7
// 1158.548 us; speedup vs baseline: 1.5600x; 1.5600x over previous
//
#include <hip/hip_runtime.h>
#include <hip/hip_bf16.h>
#include <hip/hip_fp16.h>

#define B_    8192
#define D_    1024
#define H_    4096
#define DOUT_ 1024
#define E_    8
#define MAXR  17408   // 16384 assignments + 8*128 padding

typedef float    f32x4 __attribute__((ext_vector_type(4)));
typedef _Float16 f16x8 __attribute__((ext_vector_type(8)));
typedef unsigned short u16;
typedef u16      u16x8 __attribute__((ext_vector_type(8)));
typedef u16      u16x4 __attribute__((ext_vector_type(4)));
typedef unsigned int u32;

__device__ __forceinline__ u16 f2h_bits(float f) {
  _Float16 h = (_Float16)f;
  return __builtin_bit_cast(u16, h);
}

// tanh-form gelu (max abs err vs erf-gelu ~3e-4; threshold margin 4x)
__device__ __forceinline__ float gelu_f(float v) {
  float z = 0.7978845608028654f * (v + 0.044715f * v * v * v);
  float ez = __expf(2.f * z);
  float th = 1.f - 2.f / (ez + 1.f);
  return 0.5f * v * (1.f + th);
}

// ---- workspace layout (bytes) ----
#define OFF_TOPI 512                       // int[16384]
#define OFF_TOPW (OFF_TOPI + 65536)        // float[16384]
#define OFF_ATOK (OFF_TOPW + 65536)        // int[17408]
#define OFF_WSL  (OFF_ATOK + 69632)        // float[17408]
#define OFF_XG   524288                    // u16[17408*1024] f16 (dead after gemm1)
#define OFF_W1T  (OFF_XG + 35651584)       // u16[8*4096*1024] f16 (dead after gemm1)
#define OFF_W2T  OFF_XG                    // u16[8*1024*4096] f16, ALIASES Xg+W1t
#define OFF_HB   (OFF_W1T + 67108864)      // u16[17408*4096] f16
// end = 245,891,072 bytes

__global__ void k_zero_out(float* __restrict__ out) {
  size_t i = (size_t)(blockIdx.x * 256 + threadIdx.x) * 4;
  *(f32x4*)&out[i] = (f32x4){0.f, 0.f, 0.f, 0.f};
}

__global__ void k_init(int* __restrict__ atok, float* __restrict__ wslot,
                       int* __restrict__ meta) {
  int i = blockIdx.x * 256 + threadIdx.x;
  if (i < MAXR) { atok[i] = 0; wslot[i] = 0.f; }
  if (blockIdx.x == 0 && threadIdx.x < 64) meta[threadIdx.x] = 0;
}

__global__ __launch_bounds__(256) void k_gate(
    const float* __restrict__ x, const float* __restrict__ Wg,
    const float* __restrict__ bg, int* __restrict__ counts,
    float* __restrict__ usage, int* __restrict__ topi, float* __restrict__ topw) {
  __shared__ float su[E_];
  if (threadIdx.x < E_) su[threadIdx.x] = 0.f;
  __syncthreads();
  const int lane = threadIdx.x & 63;
  const int b = blockIdx.x * 4 + (threadIdx.x >> 6);
  float p[E_] = {0.f,0.f,0.f,0.f,0.f,0.f,0.f,0.f};
  #pragma unroll
  for (int j = 0; j < 4; ++j) {
    int d = j * 256 + lane * 4;
    float4 xv = *(const float4*)&x[(size_t)b * D_ + d];
    const float* wr = &Wg[(size_t)d * E_];
    #pragma unroll
    for (int c = 0; c < 4; ++c) {
      float xc = reinterpret_cast<const float*>(&xv)[c];
      #pragma unroll
      for (int e = 0; e < E_; ++e) p[e] += xc * wr[c * E_ + e];
    }
  }
  #pragma unroll
  for (int off = 32; off >= 1; off >>= 1)
    #pragma unroll
    for (int e = 0; e < E_; ++e) p[e] += __shfl_xor(p[e], off, 64);
  float mx = -1e30f;
  #pragma unroll
  for (int e = 0; e < E_; ++e) { p[e] += bg[e]; mx = fmaxf(mx, p[e]); }
  int i0 = 0; float l0 = p[0];
  #pragma unroll
  for (int e = 1; e < E_; ++e) if (p[e] > l0) { l0 = p[e]; i0 = e; }
  int i1 = -1; float l1 = -1e30f;
  #pragma unroll
  for (int e = 0; e < E_; ++e) if (e != i0 && p[e] > l1) { l1 = p[e]; i1 = e; }
  float s = 0.f;
  #pragma unroll
  for (int e = 0; e < E_; ++e) { p[e] = expf(p[e] - mx); s += p[e]; }
  float inv = 1.f / s;
  if (lane == 0) {
    float e0 = expf(l0 - mx), e1 = expf(l1 - mx);
    float wsum = e0 + e1;
    topi[b * 2] = i0; topi[b * 2 + 1] = i1;
    topw[b * 2] = e0 / wsum; topw[b * 2 + 1] = e1 / wsum;
    atomicAdd(&counts[i0], 1);
    atomicAdd(&counts[i1], 1);
    #pragma unroll
    for (int e = 0; e < E_; ++e) atomicAdd(&su[e], p[e] * inv);
  }
  __syncthreads();
  if (threadIdx.x < E_) atomicAdd(&usage[threadIdx.x], su[threadIdx.x]);
}

__global__ void k_scan_aux(const int* __restrict__ counts, int* __restrict__ offsets,
                           const float* __restrict__ usage, float* __restrict__ auxp) {
  if (threadIdx.x == 0) {
    int off = 0;
    for (int e = 0; e < E_; ++e) { offsets[e] = off; off += (counts[e] + 127) & ~127; }
    offsets[E_] = off;
    float aux = 0.f;
    const float lu = logf(1.0f / (float)E_);
    for (int e = 0; e < E_; ++e) {
      float u = usage[e] * (1.0f / (float)B_);
      aux += u * lu - logf(u) * (1.0f / (float)E_);
    }
    *auxp = aux;
  }
}

__global__ void k_scatter(const int* __restrict__ topi, const float* __restrict__ topw,
                          const int* __restrict__ offsets, int* __restrict__ cursors,
                          int* __restrict__ atok, float* __restrict__ wslot) {
  int b = blockIdx.x * 256 + threadIdx.x;
  if (b >= B_) return;
  #pragma unroll
  for (int k = 0; k < 2; ++k) {
    int e = topi[b * 2 + k];
    int pos = atomicAdd(&cursors[e], 1);
    int slot = offsets[e] + pos;
    atok[slot] = b;
    wslot[slot] = topw[b * 2 + k];
  }
}

__global__ __launch_bounds__(256) void k_gather(const float* __restrict__ x,
                                                const int* __restrict__ atok,
                                                u16* __restrict__ Xg) {
  int slot = blockIdx.x;
  int tok = atok[slot];
  int c = threadIdx.x * 4;
  float4 v = *(const float4*)&x[(size_t)tok * D_ + c];
  const float* vf = reinterpret_cast<const float*>(&v);
  u16x4 o;
  o.x = f2h_bits(vf[0]); o.y = f2h_bits(vf[1]);
  o.z = f2h_bits(vf[2]); o.w = f2h_bits(vf[3]);
  *(u16x4*)&Xg[(size_t)slot * D_ + c] = o;
}

// convert + transpose: src [E][K][N] fp32  ->  dst [E][N][K] f16. 64x64 tiles.
__global__ __launch_bounds__(256) void k_cvt_t(const float* __restrict__ src,
                                               u16* __restrict__ dst, int K, int N) {
  const int e = blockIdx.z;
  const int kt = blockIdx.x * 64;
  const int nt = blockIdx.y * 64;
  __shared__ u16 t[64][68];
  const float* s = src + (size_t)e * K * N;
  u16* d = dst + (size_t)e * N * K;
  const int tr = threadIdx.x >> 4;
  const int tc = threadIdx.x & 15;
  #pragma unroll
  for (int i = 0; i < 4; ++i) {
    int k = tr + i * 16;
    float4 v = *(const float4*)&s[(size_t)(kt + k) * N + nt + tc * 4];
    t[k][tc*4+0] = f2h_bits(v.x); t[k][tc*4+1] = f2h_bits(v.y);
    t[k][tc*4+2] = f2h_bits(v.z); t[k][tc*4+3] = f2h_bits(v.w);
  }
  __syncthreads();
  #pragma unroll
  for (int i = 0; i < 4; ++i) {
    int n = tr + i * 16;
    u16x4 o;
    o.x = t[tc*4+0][n]; o.y = t[tc*4+1][n];
    o.z = t[tc*4+2][n]; o.w = t[tc*4+3][n];
    *(u16x4*)&d[(size_t)(nt + n) * K + kt + tc * 4] = o;
  }
}

#define GLDS(g, l) __builtin_amdgcn_global_load_lds( \
    (const u32 __attribute__((address_space(1)))*)(g), \
    (u32 __attribute__((address_space(3)))*)(l), 16, 0, 0)

#define VMWAIT(N) asm volatile("s_waitcnt vmcnt(" #N ")" ::: "memory")
#define BARRIER() do { __builtin_amdgcn_s_barrier(); \
                       asm volatile("" ::: "memory"); } while (0)

// ==== 256x256 tile, BK=32, ring-3 LDS, depth-2 counted-vmcnt pipeline ====
// LDS tile: 256 rows x 32 u16 (64B rows), XOR-swizzled in 16B chunks:
//   LDS[row][c] = src[row][c ^ swz(row)],  swz(r) = (r ^ (r>>2)) & 3
// Staged via linear-dest global_load_lds with pre-swizzled per-lane SOURCE
// (rule #21); reads XOR the same involution -> 2-way bank aliasing (free).
// Per STG each wave issues exactly 4 global_load_lds (A:2, B:2).
#define STG(kk, Ad, Bd) do { \
  const int r_ = lane >> 2; \
  const int sc_ = ((lane & 3) ^ ((r_ ^ (r_ >> 2)) & 3)) * 8; \
  _Pragma("unroll") \
  for (int c = 0; c < 2; ++c) { \
    int seg = wid * 2 + c; \
    int rowA = seg * 16 + r_; if (rowA > Alim) rowA = Alim; \
    GLDS(Ap + (size_t)rowA * LDK + (kk) + sc_, (Ad) + seg * 512); \
    GLDS(Bp + (size_t)(seg * 16 + r_) * LDK + (kk) + sc_, (Bd) + seg * 512); \
  } } while (0)

// wave-tile 128x64 (2M x 4N waves): 12 ds_read_b128 + 32 MFMA per BK=32 step
#define CMP(As, Bs) do { \
  const int r15_ = lane & 15; \
  const int coff_ = ((lane >> 4) ^ ((r15_ ^ (r15_ >> 2)) & 3)) * 8; \
  f16x8 af[8], bf[4]; \
  _Pragma("unroll") \
  for (int m = 0; m < 8; ++m) \
    af[m] = *(const f16x8*)&(As)[(wr * 128 + m * 16 + r15_) * 32 + coff_]; \
  _Pragma("unroll") \
  for (int n = 0; n < 4; ++n) \
    bf[n] = *(const f16x8*)&(Bs)[(wc * 64 + n * 16 + r15_) * 32 + coff_]; \
  _Pragma("unroll") \
  for (int m = 0; m < 8; ++m) \
    _Pragma("unroll") \
    for (int n = 0; n < 4; ++n) \
      acc[m][n] = __builtin_amdgcn_mfma_f32_16x16x32_f16(af[m], bf[n], acc[m][n], 0, 0, 0); \
  } while (0)

// one pipeline step: prefetch t+2, wait tile t complete (t+1,t+2 in flight),
// compute tile t. Two barriers isolate read(P_t) from the t+3 overwrite.
#define ITER(t, NTK, Ac, Bc, An, Bn) do { \
  if ((t) + 2 < (NTK)) { STG(((t) + 2) * 32, An, Bn); VMWAIT(8); } \
  else if ((t) + 2 == (NTK)) { VMWAIT(4); } \
  else { VMWAIT(0); } \
  BARRIER(); \
  CMP(Ac, Bc); \
  BARRIER(); \
} while (0)

// GEMM1: Hb[slot][n] = gelu( Xg[slot][:] @ W1t[e][n][:]^T + b1[e][n] )  (f16)
__global__ __launch_bounds__(512, 2) void k_gemm1(
    const u16* __restrict__ Xg, const u16* __restrict__ W1t,
    const float* __restrict__ b1, const int* __restrict__ offsets,
    u16* __restrict__ Hb) {
  // XCD-grouped decode: all 16 N-tiles of one (e,mt) share dispatch-id mod 8
  // -> same XCD -> A-tile L2-resident. Bijective over 512x16 grid.
  const int L = blockIdx.x + (int)gridDim.x * blockIdx.y;
  const int xcd = L & 7, q = L >> 3;
  const int nt = q & 15;
  const int g = ((q >> 4) << 3) | xcd;
  const int e = g >> 6, mt = g & 63;
  const int roff = offsets[e];
  const int rend = offsets[e + 1];
  const int pn = rend - roff;
  const int row0 = mt * 256;
  if (row0 >= pn) return;
  const int n0 = nt * 256;
  const int tid = threadIdx.x, lane = tid & 63, wid = tid >> 6;
  const int wr = wid >> 2, wc = wid & 3;        // 2M x 4N waves
  const int Alim = (MAXR - 1) - (roff + row0);  // clamp A-rows inside workspace
  const int LDK = D_;
  __shared__ __align__(16) u16 As0[8192], Bs0[8192], As1[8192], Bs1[8192],
                               As2[8192], Bs2[8192];           // 96 KB ring-3
  f32x4 acc[8][4] = {};
  const u16* Ap = Xg + (size_t)(roff + row0) * D_;
  const u16* Bp = W1t + (size_t)e * H_ * D_ + (size_t)n0 * D_;

  STG(0, As0, Bs0);
  STG(32, As1, Bs1);
  for (int tt = 0; tt < 30; tt += 3) {
    ITER(tt,     32, As0, Bs0, As2, Bs2);
    ITER(tt + 1, 32, As1, Bs1, As0, Bs0);
    ITER(tt + 2, 32, As2, Bs2, As1, Bs1);
  }
  ITER(30, 32, As0, Bs0, As2, Bs2);
  ITER(31, 32, As1, Bs1, As0, Bs0);

  const int rhi = (lane >> 4) * 4, cix = lane & 15;
  #pragma unroll
  for (int n = 0; n < 4; ++n) {
    int lc = wc * 64 + n * 16 + cix;
    float bv = b1[e * H_ + n0 + lc];
    #pragma unroll
    for (int m = 0; m < 8; ++m) {
      #pragma unroll
      for (int j = 0; j < 4; ++j) {
        int lr = wr * 128 + m * 16 + rhi + j;
        int gr = roff + row0 + lr;
        if (gr < rend)
          Hb[(size_t)gr * H_ + (n0 + lc)] = f2h_bits(gelu_f(acc[m][n][j] + bv));
      }
    }
  }
}

// GEMM2: out[tok][n] += wslot * ( Hb[slot][:] @ W2t[e][n][:]^T + b2[e][n] )
// 256x256 tile, K-split=2 (kbase 0 / 2048), atomic combine.
__global__ __launch_bounds__(512, 2) void k_gemm2(
    const u16* __restrict__ Hb, const u16* __restrict__ W2t,
    const float* __restrict__ b2, const int* __restrict__ offsets,
    const int* __restrict__ atok, const float* __restrict__ wslot,
    float* __restrict__ out) {
  const int L = blockIdx.x + (int)gridDim.x * blockIdx.y;   // 512 x 4 grid
  const int xcd = L & 7, q = L >> 3;
  const int nt = q & 3;
  const int g = ((q >> 2) << 3) | xcd;
  const int e = g >> 6, mt = g & 63;
  const int roff = offsets[e];
  const int rend = offsets[e + 1];
  const int pn = rend - roff;
  const int row0 = mt * 256;
  if (row0 >= pn) return;
  const int n0 = nt * 256;
  const int kbase = blockIdx.z * 2048;
  const int tid = threadIdx.x, lane = tid & 63, wid = tid >> 6;
  const int wr = wid >> 2, wc = wid & 3;
  const int Alim = (MAXR - 1) - (roff + row0);
  const int LDK = H_;
  __shared__ __align__(16) u16 As0[8192], Bs0[8192], As1[8192], Bs1[8192],
                               As2[8192], Bs2[8192];
  f32x4 acc[8][4] = {};
  const u16* Ap = Hb + (size_t)(roff + row0) * H_ + kbase;
  const u16* Bp = W2t + (size_t)e * DOUT_ * H_ + (size_t)n0 * H_ + kbase;

  STG(0, As0, Bs0);
  STG(32, As1, Bs1);
  for (int tt = 0; tt < 63; tt += 3) {
    ITER(tt,     64, As0, Bs0, As2, Bs2);
    ITER(tt + 1, 64, As1, Bs1, As0, Bs0);
    ITER(tt + 2, 64, As2, Bs2, As1, Bs1);
  }
  ITER(63, 64, As0, Bs0, As2, Bs2);

  const int rhi = (lane >> 4) * 4, cix = lane & 15;
  const int first = (kbase == 0);
  float bv[4];
  #pragma unroll
  for (int n = 0; n < 4; ++n) bv[n] = b2[e * DOUT_ + n0 + wc * 64 + n * 16 + cix];
  #pragma unroll
  for (int m = 0; m < 8; ++m) {
    #pragma unroll
    for (int j = 0; j < 4; ++j) {
      int lr = wr * 128 + m * 16 + rhi + j;
      int slot = roff + row0 + lr;
      if (slot >= rend) continue;        // row belongs to next expert's region
      float w = wslot[slot];
      if (w == 0.f) continue;            // padding slot
      int tok = atok[slot];
      float* orow = out + (size_t)tok * DOUT_ + n0;
      #pragma unroll
      for (int n = 0; n < 4; ++n) {
        int lc = wc * 64 + n * 16 + cix;
        float v = first ? w * (acc[m][n][j] + bv[n]) : w * acc[m][n][j];
        atomicAdd(&orow[lc], v);
      }
    }
  }
}

extern "C" void kernel_launch(void* const* d_in, const int* in_sizes, int n_in,
                              void* d_out, int out_size, void* d_ws, size_t ws_size,
                              hipStream_t stream) {
  const float* x  = (const float*)d_in[0];
  const float* Wg = (const float*)d_in[1];
  const float* bg = (const float*)d_in[2];
  const float* W1 = (const float*)d_in[3];
  const float* b1 = (const float*)d_in[4];
  const float* W2 = (const float*)d_in[5];
  const float* b2 = (const float*)d_in[6];
  float* out = (float*)d_out;

  char* ws = (char*)d_ws;
  int*   counts  = (int*)(ws + 0);
  int*   cursors = (int*)(ws + 32);
  int*   offsets = (int*)(ws + 64);
  float* usage   = (float*)(ws + 128);
  int*   topi    = (int*)(ws + OFF_TOPI);
  float* topw    = (float*)(ws + OFF_TOPW);
  int*   atok    = (int*)(ws + OFF_ATOK);
  float* wslot   = (float*)(ws + OFF_WSL);
  u16*   Xg      = (u16*)(ws + OFF_XG);
  u16*   W1t     = (u16*)(ws + OFF_W1T);
  u16*   W2t     = (u16*)(ws + OFF_W2T);
  u16*   Hb      = (u16*)(ws + OFF_HB);

  k_zero_out<<<B_ * DOUT_ / 1024, 256, 0, stream>>>(out);
  k_init<<<(MAXR + 255) / 256, 256, 0, stream>>>(atok, wslot, (int*)ws);
  k_gate<<<B_ / 4, 256, 0, stream>>>(x, Wg, bg, counts, usage, topi, topw);
  k_scan_aux<<<1, 64, 0, stream>>>(counts, offsets, usage, out + (size_t)B_ * DOUT_);
  k_scatter<<<B_ / 256, 256, 0, stream>>>(topi, topw, offsets, cursors, atok, wslot);
  k_gather<<<MAXR, 256, 0, stream>>>(x, atok, Xg);
  k_cvt_t<<<dim3(D_ / 64, H_ / 64, E_), 256, 0, stream>>>(W1, W1t, D_, H_);
  k_gemm1<<<dim3(E_ * 64, H_ / 256), 512, 0, stream>>>(Xg, W1t, b1, offsets, Hb);
  k_cvt_t<<<dim3(H_ / 64, DOUT_ / 64, E_), 256, 0, stream>>>(W2, W2t, H_, DOUT_);
  k_gemm2<<<dim3(E_ * 64, DOUT_ / 256, 2), 512, 0, stream>>>(Hb, W2t, b2, offsets, atok, wslot, out);
}

// Round 9
// 1011.957 us; speedup vs baseline: 1.7860x; 1.1449x over previous
//
#include <hip/hip_runtime.h>
#include <hip/hip_bf16.h>
#include <hip/hip_fp16.h>

#define B_    8192
#define D_    1024
#define H_    4096
#define DOUT_ 1024
#define E_    8
#define MAXR  17408   // 16384 assignments + 8*128 padding

typedef float    f32x4 __attribute__((ext_vector_type(4)));
typedef _Float16 f16x8 __attribute__((ext_vector_type(8)));
typedef unsigned short u16;
typedef u16      u16x8 __attribute__((ext_vector_type(8)));
typedef u16      u16x4 __attribute__((ext_vector_type(4)));
typedef unsigned int u32;

__device__ __forceinline__ u16 f2h_bits(float f) {
  _Float16 h = (_Float16)f;
  return __builtin_bit_cast(u16, h);
}

// tanh-form gelu (max abs err vs erf-gelu ~3e-4; threshold margin 4x)
__device__ __forceinline__ float gelu_f(float v) {
  float z = 0.7978845608028654f * (v + 0.044715f * v * v * v);
  float ez = __expf(2.f * z);
  float th = 1.f - 2.f / (ez + 1.f);
  return 0.5f * v * (1.f + th);
}

// ---- workspace layout (bytes) ----
#define OFF_TOPI 512                       // int[16384]
#define OFF_TOPW (OFF_TOPI + 65536)        // float[16384]
#define OFF_ATOK (OFF_TOPW + 65536)        // int[17408]
#define OFF_WSL  (OFF_ATOK + 69632)        // float[17408]
#define OFF_XG   524288                    // u16[17408*1024] f16 (dead after gemm1)
#define OFF_W1T  (OFF_XG + 35651584)       // u16[8*4096*1024] f16 (dead after gemm1)
#define OFF_W2T  OFF_XG                    // u16[8*1024*4096] f16, ALIASES Xg+W1t
#define OFF_HB   (OFF_W1T + 67108864)      // u16[17408*4096] f16
// end = 245,891,072 bytes

__global__ void k_zero_out(float* __restrict__ out) {
  size_t i = (size_t)(blockIdx.x * 256 + threadIdx.x) * 4;
  *(f32x4*)&out[i] = (f32x4){0.f, 0.f, 0.f, 0.f};
}

__global__ void k_init(int* __restrict__ atok, float* __restrict__ wslot,
                       int* __restrict__ meta) {
  int i = blockIdx.x * 256 + threadIdx.x;
  if (i < MAXR) { atok[i] = 0; wslot[i] = 0.f; }
  if (blockIdx.x == 0 && threadIdx.x < 64) meta[threadIdx.x] = 0;
}

__global__ __launch_bounds__(256) void k_gate(
    const float* __restrict__ x, const float* __restrict__ Wg,
    const float* __restrict__ bg, int* __restrict__ counts,
    float* __restrict__ usage, int* __restrict__ topi, float* __restrict__ topw) {
  __shared__ float su[E_];
  if (threadIdx.x < E_) su[threadIdx.x] = 0.f;
  __syncthreads();
  const int lane = threadIdx.x & 63;
  const int b = blockIdx.x * 4 + (threadIdx.x >> 6);
  float p[E_] = {0.f,0.f,0.f,0.f,0.f,0.f,0.f,0.f};
  #pragma unroll
  for (int j = 0; j < 4; ++j) {
    int d = j * 256 + lane * 4;
    float4 xv = *(const float4*)&x[(size_t)b * D_ + d];
    const float* wr = &Wg[(size_t)d * E_];
    #pragma unroll
    for (int c = 0; c < 4; ++c) {
      float xc = reinterpret_cast<const float*>(&xv)[c];
      #pragma unroll
      for (int e = 0; e < E_; ++e) p[e] += xc * wr[c * E_ + e];
    }
  }
  #pragma unroll
  for (int off = 32; off >= 1; off >>= 1)
    #pragma unroll
    for (int e = 0; e < E_; ++e) p[e] += __shfl_xor(p[e], off, 64);
  float mx = -1e30f;
  #pragma unroll
  for (int e = 0; e < E_; ++e) { p[e] += bg[e]; mx = fmaxf(mx, p[e]); }
  int i0 = 0; float l0 = p[0];
  #pragma unroll
  for (int e = 1; e < E_; ++e) if (p[e] > l0) { l0 = p[e]; i0 = e; }
  int i1 = -1; float l1 = -1e30f;
  #pragma unroll
  for (int e = 0; e < E_; ++e) if (e != i0 && p[e] > l1) { l1 = p[e]; i1 = e; }
  float s = 0.f;
  #pragma unroll
  for (int e = 0; e < E_; ++e) { p[e] = expf(p[e] - mx); s += p[e]; }
  float inv = 1.f / s;
  if (lane == 0) {
    float e0 = expf(l0 - mx), e1 = expf(l1 - mx);
    float wsum = e0 + e1;
    topi[b * 2] = i0; topi[b * 2 + 1] = i1;
    topw[b * 2] = e0 / wsum; topw[b * 2 + 1] = e1 / wsum;
    atomicAdd(&counts[i0], 1);
    atomicAdd(&counts[i1], 1);
    #pragma unroll
    for (int e = 0; e < E_; ++e) atomicAdd(&su[e], p[e] * inv);
  }
  __syncthreads();
  if (threadIdx.x < E_) atomicAdd(&usage[threadIdx.x], su[threadIdx.x]);
}

__global__ void k_scan_aux(const int* __restrict__ counts, int* __restrict__ offsets,
                           const float* __restrict__ usage, float* __restrict__ auxp) {
  if (threadIdx.x == 0) {
    int off = 0;
    for (int e = 0; e < E_; ++e) { offsets[e] = off; off += (counts[e] + 127) & ~127; }
    offsets[E_] = off;
    float aux = 0.f;
    const float lu = logf(1.0f / (float)E_);
    for (int e = 0; e < E_; ++e) {
      float u = usage[e] * (1.0f / (float)B_);
      aux += u * lu - logf(u) * (1.0f / (float)E_);
    }
    *auxp = aux;
  }
}

__global__ void k_scatter(const int* __restrict__ topi, const float* __restrict__ topw,
                          const int* __restrict__ offsets, int* __restrict__ cursors,
                          int* __restrict__ atok, float* __restrict__ wslot) {
  int b = blockIdx.x * 256 + threadIdx.x;
  if (b >= B_) return;
  #pragma unroll
  for (int k = 0; k < 2; ++k) {
    int e = topi[b * 2 + k];
    int pos = atomicAdd(&cursors[e], 1);
    int slot = offsets[e] + pos;
    atok[slot] = b;
    wslot[slot] = topw[b * 2 + k];
  }
}

__global__ __launch_bounds__(256) void k_gather(const float* __restrict__ x,
                                                const int* __restrict__ atok,
                                                u16* __restrict__ Xg) {
  int slot = blockIdx.x;
  int tok = atok[slot];
  int c = threadIdx.x * 4;
  float4 v = *(const float4*)&x[(size_t)tok * D_ + c];
  const float* vf = reinterpret_cast<const float*>(&v);
  u16x4 o;
  o.x = f2h_bits(vf[0]); o.y = f2h_bits(vf[1]);
  o.z = f2h_bits(vf[2]); o.w = f2h_bits(vf[3]);
  *(u16x4*)&Xg[(size_t)slot * D_ + c] = o;
}

// convert + transpose: src [E][K][N] fp32  ->  dst [E][N][K] f16. 64x64 tiles.
__global__ __launch_bounds__(256) void k_cvt_t(const float* __restrict__ src,
                                               u16* __restrict__ dst, int K, int N) {
  const int e = blockIdx.z;
  const int kt = blockIdx.x * 64;
  const int nt = blockIdx.y * 64;
  __shared__ u16 t[64][68];
  const float* s = src + (size_t)e * K * N;
  u16* d = dst + (size_t)e * N * K;
  const int tr = threadIdx.x >> 4;
  const int tc = threadIdx.x & 15;
  #pragma unroll
  for (int i = 0; i < 4; ++i) {
    int k = tr + i * 16;
    float4 v = *(const float4*)&s[(size_t)(kt + k) * N + nt + tc * 4];
    t[k][tc*4+0] = f2h_bits(v.x); t[k][tc*4+1] = f2h_bits(v.y);
    t[k][tc*4+2] = f2h_bits(v.z); t[k][tc*4+3] = f2h_bits(v.w);
  }
  __syncthreads();
  #pragma unroll
  for (int i = 0; i < 4; ++i) {
    int n = tr + i * 16;
    u16x4 o;
    o.x = t[tc*4+0][n]; o.y = t[tc*4+1][n];
    o.z = t[tc*4+2][n]; o.w = t[tc*4+3][n];
    *(u16x4*)&d[(size_t)(nt + n) * K + kt + tc * 4] = o;
  }
}

#define GLDS(g, l) __builtin_amdgcn_global_load_lds( \
    (const u32 __attribute__((address_space(1)))*)(g), \
    (u32 __attribute__((address_space(3)))*)(l), 16, 0, 0)

// ==== 128x128 tile, BK=32, dbuf 32KB LDS, issue-early, 4 waves (2Mx2N) ====
// LDS: one named array SM[16384] u16; A0@0 B0@4096 A1@8192 B1@12288 (u16 idx).
// Tile = 128 rows x 32 u16, row = 64B. XOR source-swizzle (R7-proven pair):
//   LDS[row][chunk] = src[row][chunk ^ ((row^(row>>2))&3)]  (16B chunks)
// 8 segments of 16 rows; seg = wid*2+c; segment = 16 rows * 32 u16 = 512 u16.
// Per-wave dest base = seg*512 u16 (1024B), lane writes byte lane*16.
#define STG(LDK, kk, Aoff, Boff) do { \
  const int r_ = lane >> 2; \
  const int sc_ = ((lane & 3) ^ ((r_ ^ (r_ >> 2)) & 3)) * 8; \
  _Pragma("unroll") \
  for (int c = 0; c < 2; ++c) { \
    int seg = wid * 2 + c; \
    GLDS(Ap + (size_t)(seg * 16 + r_) * (LDK) + (kk) + sc_, SM + (Aoff) + seg * 512); \
    GLDS(Bp + (size_t)(seg * 16 + r_) * (LDK) + (kk) + sc_, SM + (Boff) + seg * 512); \
  } } while (0)

// wave-tile 64x64: 8 ds_read_b128 + 16 MFMA per BK=32 step
#define CMP(Aoff, Boff) do { \
  const int r15_ = lane & 15; \
  const int co_ = (((lane >> 4) ^ ((r15_ ^ (r15_ >> 2)) & 3)) * 8); \
  f16x8 af[4], bf[4]; \
  _Pragma("unroll") \
  for (int m = 0; m < 4; ++m) \
    af[m] = *(const f16x8*)&SM[(Aoff) + (wr * 64 + m * 16 + r15_) * 32 + co_]; \
  _Pragma("unroll") \
  for (int n = 0; n < 4; ++n) \
    bf[n] = *(const f16x8*)&SM[(Boff) + (wc * 64 + n * 16 + r15_) * 32 + co_]; \
  _Pragma("unroll") \
  for (int m = 0; m < 4; ++m) \
    _Pragma("unroll") \
    for (int n = 0; n < 4; ++n) \
      acc[m][n] = __builtin_amdgcn_mfma_f32_16x16x32_f16(af[m], bf[n], acc[m][n], 0, 0, 0); \
  } while (0)

// GEMM1: Hb[slot][n] = gelu( Xg[slot][:] @ W1t[e][n][:]^T + b1[e][n] )  (f16)
// Grid 16384 1D; XCD-grouped decode: 32 nt of one (e,mt) share L&7 -> same XCD.
__global__ __launch_bounds__(256) void k_gemm1(
    const u16* __restrict__ Xg, const u16* __restrict__ W1t,
    const float* __restrict__ b1, const int* __restrict__ offsets,
    u16* __restrict__ Hb) {
  const int L = blockIdx.x;
  const int xcd = L & 7, q = L >> 3;
  const int nt = q & 31;
  const int g = ((q >> 5) << 3) | xcd;
  const int e = g >> 6, mt = g & 63;
  const int roff = offsets[e];
  const int pn = offsets[e + 1] - roff;
  const int row0 = mt * 128;
  if (row0 >= pn) return;      // 128-tiles never straddle 128-padded regions
  const int n0 = nt * 128;
  const int tid = threadIdx.x, lane = tid & 63, wid = tid >> 6;
  const int wr = wid >> 1, wc = wid & 1;
  __shared__ __align__(16) u16 SM[16384];
  f32x4 acc[4][4] = {};
  const u16* Ap = Xg + (size_t)(roff + row0) * D_;
  const u16* Bp = W1t + (size_t)e * H_ * D_ + (size_t)n0 * D_;

  STG(D_, 0, 0, 4096);
  __syncthreads();
  for (int t = 0; t < 32; t += 2) {
    STG(D_, (t + 1) * 32, 8192, 12288);
    CMP(0, 4096);
    __syncthreads();
    if (t + 2 < 32) STG(D_, (t + 2) * 32, 0, 4096);
    CMP(8192, 12288);
    __syncthreads();
  }
  // epilogue: bias+gelu -> LDS (64 x 136, 272B rows = 16B-aligned) -> 16B stores
  const int rhi = (lane >> 4) * 4, cix = lane & 15;
  float bv[4];
  #pragma unroll
  for (int n = 0; n < 4; ++n) bv[n] = b1[e * H_ + n0 + wc * 64 + n * 16 + cix];
  #pragma unroll
  for (int r = 0; r < 2; ++r) {
    if (wr == r) {
      #pragma unroll
      for (int m = 0; m < 4; ++m)
        #pragma unroll
        for (int n = 0; n < 4; ++n)
          #pragma unroll
          for (int j = 0; j < 4; ++j)
            SM[(m * 16 + rhi + j) * 136 + wc * 64 + n * 16 + cix] =
                f2h_bits(gelu_f(acc[m][n][j] + bv[n]));
    }
    __syncthreads();
    {
      const int rl = tid >> 2, co = (tid & 3) * 32;
      u16* dst = &Hb[(size_t)(roff + row0 + r * 64 + rl) * H_ + n0 + co];
      const u16* srcp = &SM[rl * 136 + co];
      #pragma unroll
      for (int qq = 0; qq < 4; ++qq)
        *(u16x8*)(dst + qq * 8) = *(const u16x8*)(srcp + qq * 8);
    }
    __syncthreads();
  }
}

// GEMM2: out[tok][n] += wslot * ( Hb[slot][:] @ W2t[e][n][:]^T + b2[e][n] )
// Full K=4096 per block (no K-split). Grid 4096 1D, XCD-grouped.
__global__ __launch_bounds__(256) void k_gemm2(
    const u16* __restrict__ Hb, const u16* __restrict__ W2t,
    const float* __restrict__ b2, const int* __restrict__ offsets,
    const int* __restrict__ atok, const float* __restrict__ wslot,
    float* __restrict__ out) {
  const int L = blockIdx.x;
  const int xcd = L & 7, q = L >> 3;
  const int nt = q & 7;
  const int g = ((q >> 3) << 3) | xcd;
  const int e = g >> 6, mt = g & 63;
  const int roff = offsets[e];
  const int pn = offsets[e + 1] - roff;
  const int row0 = mt * 128;
  if (row0 >= pn) return;
  const int n0 = nt * 128;
  const int tid = threadIdx.x, lane = tid & 63, wid = tid >> 6;
  const int wr = wid >> 1, wc = wid & 1;
  __shared__ __align__(16) u16 SM[16384];
  f32x4 acc[4][4] = {};
  const u16* Ap = Hb + (size_t)(roff + row0) * H_;
  const u16* Bp = W2t + (size_t)e * DOUT_ * H_ + (size_t)n0 * H_;

  STG(H_, 0, 0, 4096);
  __syncthreads();
  for (int t = 0; t < 128; t += 2) {
    STG(H_, (t + 1) * 32, 8192, 12288);
    CMP(0, 4096);
    __syncthreads();
    if (t + 2 < 128) STG(H_, (t + 2) * 32, 0, 4096);
    CMP(8192, 12288);
    __syncthreads();
  }
  const int rhi = (lane >> 4) * 4, cix = lane & 15;
  float bv[4];
  #pragma unroll
  for (int n = 0; n < 4; ++n) bv[n] = b2[e * DOUT_ + n0 + wc * 64 + n * 16 + cix];
  #pragma unroll
  for (int m = 0; m < 4; ++m) {
    #pragma unroll
    for (int j = 0; j < 4; ++j) {
      int slot = roff + row0 + wr * 64 + m * 16 + rhi + j;
      float w = wslot[slot];
      if (w == 0.f) continue;   // padding slot
      int tok = atok[slot];
      float* orow = out + (size_t)tok * DOUT_ + n0;
      #pragma unroll
      for (int n = 0; n < 4; ++n) {
        int lc = wc * 64 + n * 16 + cix;
        atomicAdd(&orow[lc], w * (acc[m][n][j] + bv[n]));
      }
    }
  }
}

extern "C" void kernel_launch(void* const* d_in, const int* in_sizes, int n_in,
                              void* d_out, int out_size, void* d_ws, size_t ws_size,
                              hipStream_t stream) {
  const float* x  = (const float*)d_in[0];
  const float* Wg = (const float*)d_in[1];
  const float* bg = (const float*)d_in[2];
  const float* W1 = (const float*)d_in[3];
  const float* b1 = (const float*)d_in[4];
  const float* W2 = (const float*)d_in[5];
  const float* b2 = (const float*)d_in[6];
  float* out = (float*)d_out;

  char* ws = (char*)d_ws;
  int*   counts  = (int*)(ws + 0);
  int*   cursors = (int*)(ws + 32);
  int*   offsets = (int*)(ws + 64);
  float* usage   = (float*)(ws + 128);
  int*   topi    = (int*)(ws + OFF_TOPI);
  float* topw    = (float*)(ws + OFF_TOPW);
  int*   atok    = (int*)(ws + OFF_ATOK);
  float* wslot   = (float*)(ws + OFF_WSL);
  u16*   Xg      = (u16*)(ws + OFF_XG);
  u16*   W1t     = (u16*)(ws + OFF_W1T);
  u16*   W2t     = (u16*)(ws + OFF_W2T);
  u16*   Hb      = (u16*)(ws + OFF_HB);

  k_zero_out<<<B_ * DOUT_ / 1024, 256, 0, stream>>>(out);
  k_init<<<(MAXR + 255) / 256, 256, 0, stream>>>(atok, wslot, (int*)ws);
  k_gate<<<B_ / 4, 256, 0, stream>>>(x, Wg, bg, counts, usage, topi, topw);
  k_scan_aux<<<1, 64, 0, stream>>>(counts, offsets, usage, out + (size_t)B_ * DOUT_);
  k_scatter<<<B_ / 256, 256, 0, stream>>>(topi, topw, offsets, cursors, atok, wslot);
  k_gather<<<MAXR, 256, 0, stream>>>(x, atok, Xg);
  k_cvt_t<<<dim3(D_ / 64, H_ / 64, E_), 256, 0, stream>>>(W1, W1t, D_, H_);
  k_gemm1<<<E_ * 64 * 32, 256, 0, stream>>>(Xg, W1t, b1, offsets, Hb);
  k_cvt_t<<<dim3(H_ / 64, DOUT_ / 64, E_), 256, 0, stream>>>(W2, W2t, H_, DOUT_);
  k_gemm2<<<E_ * 64 * 8, 256, 0, stream>>>(Hb, W2t, b2, offsets, atok, wslot, out);
}

// Round 10
// 926.611 us; speedup vs baseline: 1.9505x; 1.0921x over previous
//
#include <hip/hip_runtime.h>
#include <hip/hip_bf16.h>
#include <hip/hip_fp16.h>

#define B_    8192
#define D_    1024
#define H_    4096
#define DOUT_ 1024
#define E_    8
#define MAXR  17408   // 16384 assignments + 8*128 padding

typedef float    f32x4 __attribute__((ext_vector_type(4)));
typedef _Float16 f16x8 __attribute__((ext_vector_type(8)));
typedef unsigned short u16;
typedef u16      u16x8 __attribute__((ext_vector_type(8)));
typedef u16      u16x4 __attribute__((ext_vector_type(4)));
typedef unsigned int u32;

__device__ __forceinline__ u16 f2h_bits(float f) {
  _Float16 h = (_Float16)f;
  return __builtin_bit_cast(u16, h);
}

// tanh-form gelu (max abs err vs erf-gelu ~3e-4; threshold margin 4x)
__device__ __forceinline__ float gelu_f(float v) {
  float z = 0.7978845608028654f * (v + 0.044715f * v * v * v);
  float ez = __expf(2.f * z);
  float th = 1.f - 2.f / (ez + 1.f);
  return 0.5f * v * (1.f + th);
}

// ---- workspace layout (bytes) ----
#define OFF_TOPI 512                       // int[16384]
#define OFF_TOPW (OFF_TOPI + 65536)        // float[16384]
#define OFF_ATOK (OFF_TOPW + 65536)        // int[17408]
#define OFF_WSL  (OFF_ATOK + 69632)        // float[17408]
#define OFF_XG   524288                    // u16[17408*1024] f16 (dead after gemm1)
#define OFF_W1T  (OFF_XG + 35651584)       // u16[8*4096*1024] f16 (dead after gemm1)
#define OFF_W2T  OFF_XG                    // u16[8*1024*4096] f16, ALIASES Xg+W1t
#define OFF_HB   (OFF_W1T + 67108864)      // u16[17408*4096] f16
// end = 245,891,072 bytes

__global__ void k_zero_out(float* __restrict__ out) {
  size_t i = (size_t)(blockIdx.x * 256 + threadIdx.x) * 4;
  *(f32x4*)&out[i] = (f32x4){0.f, 0.f, 0.f, 0.f};
}

__global__ void k_init(int* __restrict__ atok, float* __restrict__ wslot,
                       int* __restrict__ meta) {
  int i = blockIdx.x * 256 + threadIdx.x;
  if (i < MAXR) { atok[i] = 0; wslot[i] = 0.f; }
  if (blockIdx.x == 0 && threadIdx.x < 64) meta[threadIdx.x] = 0;
}

__global__ __launch_bounds__(256) void k_gate(
    const float* __restrict__ x, const float* __restrict__ Wg,
    const float* __restrict__ bg, int* __restrict__ counts,
    float* __restrict__ usage, int* __restrict__ topi, float* __restrict__ topw) {
  __shared__ float su[E_];
  if (threadIdx.x < E_) su[threadIdx.x] = 0.f;
  __syncthreads();
  const int lane = threadIdx.x & 63;
  const int b = blockIdx.x * 4 + (threadIdx.x >> 6);
  float p[E_] = {0.f,0.f,0.f,0.f,0.f,0.f,0.f,0.f};
  #pragma unroll
  for (int j = 0; j < 4; ++j) {
    int d = j * 256 + lane * 4;
    float4 xv = *(const float4*)&x[(size_t)b * D_ + d];
    const float* wr = &Wg[(size_t)d * E_];
    #pragma unroll
    for (int c = 0; c < 4; ++c) {
      float xc = reinterpret_cast<const float*>(&xv)[c];
      #pragma unroll
      for (int e = 0; e < E_; ++e) p[e] += xc * wr[c * E_ + e];
    }
  }
  #pragma unroll
  for (int off = 32; off >= 1; off >>= 1)
    #pragma unroll
    for (int e = 0; e < E_; ++e) p[e] += __shfl_xor(p[e], off, 64);
  float mx = -1e30f;
  #pragma unroll
  for (int e = 0; e < E_; ++e) { p[e] += bg[e]; mx = fmaxf(mx, p[e]); }
  int i0 = 0; float l0 = p[0];
  #pragma unroll
  for (int e = 1; e < E_; ++e) if (p[e] > l0) { l0 = p[e]; i0 = e; }
  int i1 = -1; float l1 = -1e30f;
  #pragma unroll
  for (int e = 0; e < E_; ++e) if (e != i0 && p[e] > l1) { l1 = p[e]; i1 = e; }
  float s = 0.f;
  #pragma unroll
  for (int e = 0; e < E_; ++e) { p[e] = expf(p[e] - mx); s += p[e]; }
  float inv = 1.f / s;
  if (lane == 0) {
    float e0 = expf(l0 - mx), e1 = expf(l1 - mx);
    float wsum = e0 + e1;
    topi[b * 2] = i0; topi[b * 2 + 1] = i1;
    topw[b * 2] = e0 / wsum; topw[b * 2 + 1] = e1 / wsum;
    atomicAdd(&counts[i0], 1);
    atomicAdd(&counts[i1], 1);
    #pragma unroll
    for (int e = 0; e < E_; ++e) atomicAdd(&su[e], p[e] * inv);
  }
  __syncthreads();
  if (threadIdx.x < E_) atomicAdd(&usage[threadIdx.x], su[threadIdx.x]);
}

__global__ void k_scan_aux(const int* __restrict__ counts, int* __restrict__ offsets,
                           const float* __restrict__ usage, float* __restrict__ auxp) {
  if (threadIdx.x == 0) {
    int off = 0;
    for (int e = 0; e < E_; ++e) { offsets[e] = off; off += (counts[e] + 127) & ~127; }
    offsets[E_] = off;
    float aux = 0.f;
    const float lu = logf(1.0f / (float)E_);
    for (int e = 0; e < E_; ++e) {
      float u = usage[e] * (1.0f / (float)B_);
      aux += u * lu - logf(u) * (1.0f / (float)E_);
    }
    *auxp = aux;
  }
}

__global__ void k_scatter(const int* __restrict__ topi, const float* __restrict__ topw,
                          const int* __restrict__ offsets, int* __restrict__ cursors,
                          int* __restrict__ atok, float* __restrict__ wslot) {
  int b = blockIdx.x * 256 + threadIdx.x;
  if (b >= B_) return;
  #pragma unroll
  for (int k = 0; k < 2; ++k) {
    int e = topi[b * 2 + k];
    int pos = atomicAdd(&cursors[e], 1);
    int slot = offsets[e] + pos;
    atok[slot] = b;
    wslot[slot] = topw[b * 2 + k];
  }
}

__global__ __launch_bounds__(256) void k_gather(const float* __restrict__ x,
                                                const int* __restrict__ atok,
                                                u16* __restrict__ Xg) {
  int slot = blockIdx.x;
  int tok = atok[slot];
  int c = threadIdx.x * 4;
  float4 v = *(const float4*)&x[(size_t)tok * D_ + c];
  const float* vf = reinterpret_cast<const float*>(&v);
  u16x4 o;
  o.x = f2h_bits(vf[0]); o.y = f2h_bits(vf[1]);
  o.z = f2h_bits(vf[2]); o.w = f2h_bits(vf[3]);
  *(u16x4*)&Xg[(size_t)slot * D_ + c] = o;
}

// convert + transpose: src [E][K][N] fp32  ->  dst [E][N][K] f16. 64x64 tiles.
__global__ __launch_bounds__(256) void k_cvt_t(const float* __restrict__ src,
                                               u16* __restrict__ dst, int K, int N) {
  const int e = blockIdx.z;
  const int kt = blockIdx.x * 64;
  const int nt = blockIdx.y * 64;
  __shared__ u16 t[64][68];
  const float* s = src + (size_t)e * K * N;
  u16* d = dst + (size_t)e * N * K;
  const int tr = threadIdx.x >> 4;
  const int tc = threadIdx.x & 15;
  #pragma unroll
  for (int i = 0; i < 4; ++i) {
    int k = tr + i * 16;
    float4 v = *(const float4*)&s[(size_t)(kt + k) * N + nt + tc * 4];
    t[k][tc*4+0] = f2h_bits(v.x); t[k][tc*4+1] = f2h_bits(v.y);
    t[k][tc*4+2] = f2h_bits(v.z); t[k][tc*4+3] = f2h_bits(v.w);
  }
  __syncthreads();
  #pragma unroll
  for (int i = 0; i < 4; ++i) {
    int n = tr + i * 16;
    u16x4 o;
    o.x = t[tc*4+0][n]; o.y = t[tc*4+1][n];
    o.z = t[tc*4+2][n]; o.w = t[tc*4+3][n];
    *(u16x4*)&d[(size_t)(nt + n) * K + kt + tc * 4] = o;
  }
}

#define GLDS(g, l) __builtin_amdgcn_global_load_lds( \
    (const u32 __attribute__((address_space(1)))*)(g), \
    (u32 __attribute__((address_space(3)))*)(l), 16, 0, 0)

// ==== 128x128 tile, BK=32, dbuf 32KB LDS, issue-early, 4 waves (2Mx2N) ====
// (R9-proven core, unchanged.) LDS: SM[16384] u16; A0@0 B0@4096 A1@8192 B1@12288.
// XOR source-swizzle pair: LDS[row][chunk] = src[row][chunk ^ ((row^(row>>2))&3)]
#define STG(LDK, kk, Aoff, Boff) do { \
  const int r_ = lane >> 2; \
  const int sc_ = ((lane & 3) ^ ((r_ ^ (r_ >> 2)) & 3)) * 8; \
  _Pragma("unroll") \
  for (int c = 0; c < 2; ++c) { \
    int seg = wid * 2 + c; \
    GLDS(Ap + (size_t)(seg * 16 + r_) * (LDK) + (kk) + sc_, SM + (Aoff) + seg * 512); \
    GLDS(Bp + (size_t)(seg * 16 + r_) * (LDK) + (kk) + sc_, SM + (Boff) + seg * 512); \
  } } while (0)

#define CMP(Aoff, Boff) do { \
  const int r15_ = lane & 15; \
  const int co_ = (((lane >> 4) ^ ((r15_ ^ (r15_ >> 2)) & 3)) * 8); \
  f16x8 af[4], bf[4]; \
  _Pragma("unroll") \
  for (int m = 0; m < 4; ++m) \
    af[m] = *(const f16x8*)&SM[(Aoff) + (wr * 64 + m * 16 + r15_) * 32 + co_]; \
  _Pragma("unroll") \
  for (int n = 0; n < 4; ++n) \
    bf[n] = *(const f16x8*)&SM[(Boff) + (wc * 64 + n * 16 + r15_) * 32 + co_]; \
  _Pragma("unroll") \
  for (int m = 0; m < 4; ++m) \
    _Pragma("unroll") \
    for (int n = 0; n < 4; ++n) \
      acc[m][n] = __builtin_amdgcn_mfma_f32_16x16x32_f16(af[m], bf[n], acc[m][n], 0, 0, 0); \
  } while (0)

// GEMM1: Hb[row][n] = gelu( Xg[row][:] @ W1t[e][n][:]^T + b1[e][n] )  (f16)
// DENSE grid over compact padded-row space: 136 M-tiles x 32 N-tiles, mt-major.
// Every 128-row tile lies in exactly one expert region (regions 128-aligned).
__global__ __launch_bounds__(256) void k_gemm1(
    const u16* __restrict__ Xg, const u16* __restrict__ W1t,
    const float* __restrict__ b1, const int* __restrict__ offsets,
    u16* __restrict__ Hb) {
  const int L = blockIdx.x;
  const int mtile = L >> 5;          // A-sharing blocks adjacent in dispatch
  const int nt = L & 31;
  const int row0 = mtile * 128;
  if (row0 >= offsets[E_]) return;   // only tail tiles beyond data
  int e = 0;
  #pragma unroll
  for (int i = 1; i < E_; ++i) e = (row0 >= offsets[i]) ? i : e;
  const int n0 = nt * 128;
  const int tid = threadIdx.x, lane = tid & 63, wid = tid >> 6;
  const int wr = wid >> 1, wc = wid & 1;
  __shared__ __align__(16) u16 SM[16384];
  f32x4 acc[4][4] = {};
  const u16* Ap = Xg + (size_t)row0 * D_;
  const u16* Bp = W1t + (size_t)e * H_ * D_ + (size_t)n0 * D_;

  STG(D_, 0, 0, 4096);
  __syncthreads();
  for (int t = 0; t < 32; t += 2) {
    STG(D_, (t + 1) * 32, 8192, 12288);
    CMP(0, 4096);
    __syncthreads();
    if (t + 2 < 32) STG(D_, (t + 2) * 32, 0, 4096);
    CMP(8192, 12288);
    __syncthreads();
  }
  // epilogue: bias+gelu -> LDS (64 x 136, 272B rows = 16B-aligned) -> 16B stores
  const int rhi = (lane >> 4) * 4, cix = lane & 15;
  float bv[4];
  #pragma unroll
  for (int n = 0; n < 4; ++n) bv[n] = b1[e * H_ + n0 + wc * 64 + n * 16 + cix];
  #pragma unroll
  for (int r = 0; r < 2; ++r) {
    if (wr == r) {
      #pragma unroll
      for (int m = 0; m < 4; ++m)
        #pragma unroll
        for (int n = 0; n < 4; ++n)
          #pragma unroll
          for (int j = 0; j < 4; ++j)
            SM[(m * 16 + rhi + j) * 136 + wc * 64 + n * 16 + cix] =
                f2h_bits(gelu_f(acc[m][n][j] + bv[n]));
    }
    __syncthreads();
    {
      const int rl = tid >> 2, co = (tid & 3) * 32;
      u16* dst = &Hb[(size_t)(row0 + r * 64 + rl) * H_ + n0 + co];
      const u16* srcp = &SM[rl * 136 + co];
      #pragma unroll
      for (int qq = 0; qq < 4; ++qq)
        *(u16x8*)(dst + qq * 8) = *(const u16x8*)(srcp + qq * 8);
    }
    __syncthreads();
  }
}

// GEMM2: out[tok][n] += wslot * ( Hb[row][:] @ W2t[e][n][:]^T + b2[e][n] )
// DENSE grid: 136 M-tiles x 8 N-tiles (1088 blocks, fully co-resident).
__global__ __launch_bounds__(256) void k_gemm2(
    const u16* __restrict__ Hb, const u16* __restrict__ W2t,
    const float* __restrict__ b2, const int* __restrict__ offsets,
    const int* __restrict__ atok, const float* __restrict__ wslot,
    float* __restrict__ out) {
  const int L = blockIdx.x;
  const int mtile = L >> 3;
  const int nt = L & 7;
  const int row0 = mtile * 128;
  if (row0 >= offsets[E_]) return;
  int e = 0;
  #pragma unroll
  for (int i = 1; i < E_; ++i) e = (row0 >= offsets[i]) ? i : e;
  const int n0 = nt * 128;
  const int tid = threadIdx.x, lane = tid & 63, wid = tid >> 6;
  const int wr = wid >> 1, wc = wid & 1;
  __shared__ __align__(16) u16 SM[16384];
  f32x4 acc[4][4] = {};
  const u16* Ap = Hb + (size_t)row0 * H_;
  const u16* Bp = W2t + (size_t)e * DOUT_ * H_ + (size_t)n0 * H_;

  STG(H_, 0, 0, 4096);
  __syncthreads();
  for (int t = 0; t < 128; t += 2) {
    STG(H_, (t + 1) * 32, 8192, 12288);
    CMP(0, 4096);
    __syncthreads();
    if (t + 2 < 128) STG(H_, (t + 2) * 32, 0, 4096);
    CMP(8192, 12288);
    __syncthreads();
  }
  const int rhi = (lane >> 4) * 4, cix = lane & 15;
  float bv[4];
  #pragma unroll
  for (int n = 0; n < 4; ++n) bv[n] = b2[e * DOUT_ + n0 + wc * 64 + n * 16 + cix];
  #pragma unroll
  for (int m = 0; m < 4; ++m) {
    #pragma unroll
    for (int j = 0; j < 4; ++j) {
      int slot = row0 + wr * 64 + m * 16 + rhi + j;
      float w = wslot[slot];
      if (w == 0.f) continue;   // padding slot
      int tok = atok[slot];
      float* orow = out + (size_t)tok * DOUT_ + n0;
      #pragma unroll
      for (int n = 0; n < 4; ++n) {
        int lc = wc * 64 + n * 16 + cix;
        atomicAdd(&orow[lc], w * (acc[m][n][j] + bv[n]));
      }
    }
  }
}

extern "C" void kernel_launch(void* const* d_in, const int* in_sizes, int n_in,
                              void* d_out, int out_size, void* d_ws, size_t ws_size,
                              hipStream_t stream) {
  const float* x  = (const float*)d_in[0];
  const float* Wg = (const float*)d_in[1];
  const float* bg = (const float*)d_in[2];
  const float* W1 = (const float*)d_in[3];
  const float* b1 = (const float*)d_in[4];
  const float* W2 = (const float*)d_in[5];
  const float* b2 = (const float*)d_in[6];
  float* out = (float*)d_out;

  char* ws = (char*)d_ws;
  int*   counts  = (int*)(ws + 0);
  int*   cursors = (int*)(ws + 32);
  int*   offsets = (int*)(ws + 64);
  float* usage   = (float*)(ws + 128);
  int*   topi    = (int*)(ws + OFF_TOPI);
  float* topw    = (float*)(ws + OFF_TOPW);
  int*   atok    = (int*)(ws + OFF_ATOK);
  float* wslot   = (float*)(ws + OFF_WSL);
  u16*   Xg      = (u16*)(ws + OFF_XG);
  u16*   W1t     = (u16*)(ws + OFF_W1T);
  u16*   W2t     = (u16*)(ws + OFF_W2T);
  u16*   Hb      = (u16*)(ws + OFF_HB);

  k_zero_out<<<B_ * DOUT_ / 1024, 256, 0, stream>>>(out);
  k_init<<<(MAXR + 255) / 256, 256, 0, stream>>>(atok, wslot, (int*)ws);
  k_gate<<<B_ / 4, 256, 0, stream>>>(x, Wg, bg, counts, usage, topi, topw);
  k_scan_aux<<<1, 64, 0, stream>>>(counts, offsets, usage, out + (size_t)B_ * DOUT_);
  k_scatter<<<B_ / 256, 256, 0, stream>>>(topi, topw, offsets, cursors, atok, wslot);
  k_gather<<<MAXR, 256, 0, stream>>>(x, atok, Xg);
  k_cvt_t<<<dim3(D_ / 64, H_ / 64, E_), 256, 0, stream>>>(W1, W1t, D_, H_);
  k_gemm1<<<(MAXR / 128) * 32, 256, 0, stream>>>(Xg, W1t, b1, offsets, Hb);
  k_cvt_t<<<dim3(H_ / 64, DOUT_ / 64, E_), 256, 0, stream>>>(W2, W2t, H_, DOUT_);
  k_gemm2<<<(MAXR / 128) * 8, 256, 0, stream>>>(Hb, W2t, b2, offsets, atok, wslot, out);
}